// Round 1
// baseline (808.222 us; speedup 1.0000x reference)
//
#include <hip/hip_runtime.h>
#include <hip/hip_bf16.h>

typedef __bf16 bf16;
typedef bf16 bf16x8 __attribute__((ext_vector_type(8)));
typedef bf16 bf16x4 __attribute__((ext_vector_type(4)));
typedef float f32x4 __attribute__((ext_vector_type(4)));

#define SCALE 0.17677669529663687f  // 1/sqrt(32)

// LDS element offsets (bf16 units)
#define OFF_XB0 0
#define OFF_XB1 12800
#define OFF_Q   25600
#define OFF_K   38400
#define OFF_V   51200   // vT: [6 heads][32 d][72 stride]
#define OFF_P   65024   // per-wave P: [32 n][72 stride]
#define SMEM_ELEMS 74240

// ---------------- prep kernel: weight transpose->bf16, bias gather ----------------
// ws layout (bytes): wqkvT bf16 [576][192] @0 ; projT bf16 [192][192] @221184 ;
//                    biasB f32  [6][16][64][4] @294912  (total 393216 B)
__global__ void wattn_prep(const float* __restrict__ wq, const float* __restrict__ wkv,
                           const float* __restrict__ bias_table, const float* __restrict__ proj_w,
                           bf16* __restrict__ wqkvT, bf16* __restrict__ projT,
                           float* __restrict__ biasB)
{
    int t = blockIdx.x * 256 + threadIdx.x;
    if (t < 110592) {                       // wqkvT[n][k] = W[k][n]
        int n = t / 192, k = t % 192;
        float v = (n < 192) ? wq[k * 192 + n] : wkv[k * 384 + (n - 192)];
        wqkvT[t] = (bf16)v;
    } else if (t < 147456) {                // projT[n][k] = proj_w[k][n]
        int e = t - 110592;
        int n = e / 192, k = e % 192;
        projT[e] = (bf16)proj_w[k * 192 + n];
    } else if (t < 172032) {                // biasB[h][m>>2][n][m&3] = bias[h][n][m]
        int e = t - 147456;
        int h  = e >> 12;
        int mb = (e >> 8) & 15;
        int n  = (e >> 2) & 63;
        int mr = e & 3;
        int m  = mb * 4 + mr;
        // tf.meshgrid 'xy': idx[n][m] = ((n%8)-(m%8)+7)*15 + ((n/8)-(m/8)+7)
        int idx = ((n & 7) - (m & 7) + 7) * 15 + ((n >> 3) - (m >> 3) + 7);
        biasB[e] = bias_table[idx * 6 + h];
    }
}

// ---------------- fused main kernel ----------------
__global__ __launch_bounds__(256, 1)
void wattn_main(const float* __restrict__ x, const bf16* __restrict__ wqkvT,
                const float* __restrict__ bq, const float* __restrict__ bkv,
                const bf16* __restrict__ projT, const float* __restrict__ biasB,
                const float* __restrict__ proj_b, float* __restrict__ outg,
                int B, int nIter)
{
    __shared__ __align__(16) bf16 smem[SMEM_ELEMS];
    const int tid = threadIdx.x;
    const int li  = tid & 15;        // lane % 16
    const int gi  = (tid >> 4) & 3;  // lane / 16 within wave
    const int w   = tid >> 6;        // wave 0..3
    const int bid = blockIdx.x;

    bf16* q  = smem + OFF_Q;
    bf16* kb = smem + OFF_K;
    bf16* vt = smem + OFF_V;
    bf16* Pw = smem + OFF_P + w * (32 * 72);

    int win0 = bid * nIter;
    int nw = B - win0; if (nw > nIter) nw = nIter; if (nw <= 0) return;

    const f32x4 fzero = {0.f, 0.f, 0.f, 0.f};

    // prologue: stage first window into buffer 0
    {
        const float4* xg = (const float4*)(x + (size_t)win0 * 12288);
        float4 px[12];
#pragma unroll
        for (int i = 0; i < 12; ++i) px[i] = xg[i * 256 + tid];
#pragma unroll
        for (int i = 0; i < 12; ++i) {
            int f = (i * 256 + tid) * 4;
            int r = f / 192, c = f % 192;
            bf16x4 v; v[0]=(bf16)px[i].x; v[1]=(bf16)px[i].y; v[2]=(bf16)px[i].z; v[3]=(bf16)px[i].w;
            *(bf16x4*)&smem[OFF_XB0 + r * 200 + c] = v;
        }
    }
    __syncthreads();

    int cur = 0;
    for (int it = 0; it < nw; ++it) {
        int win = win0 + it;
        bf16* xb = smem + (cur ? OFF_XB1 : OFF_XB0);

        // ================= QKV GEMM: [64,192]x[192,576] =================
        f32x4 acc[4][9];
#pragma unroll
        for (int rt = 0; rt < 4; ++rt)
#pragma unroll
            for (int ct = 0; ct < 9; ++ct) acc[rt][ct] = fzero;
#pragma unroll
        for (int kk = 0; kk < 6; ++kk) {
            bf16x8 a[4], bw[9];
#pragma unroll
            for (int rt = 0; rt < 4; ++rt)
                a[rt] = *(const bf16x8*)&xb[(rt * 16 + li) * 200 + kk * 32 + gi * 8];
#pragma unroll
            for (int ct = 0; ct < 9; ++ct)
                bw[ct] = *(const bf16x8*)&wqkvT[(size_t)(w * 144 + ct * 16 + li) * 192 + kk * 32 + gi * 8];
#pragma unroll
            for (int ct = 0; ct < 9; ++ct)
#pragma unroll
                for (int rt = 0; rt < 4; ++rt)
                    acc[rt][ct] = __builtin_amdgcn_mfma_f32_16x16x32_bf16(a[rt], bw[ct], acc[rt][ct], 0, 0, 0);
        }
        // epilogue: bias + leaky (+SCALE for q), scatter to q / k / vT
#pragma unroll
        for (int ct = 0; ct < 9; ++ct) {
            int n0 = w * 144 + ct * 16;
            float bias = (n0 < 192) ? bq[n0 + li] : bkv[n0 - 192 + li];
#pragma unroll
            for (int rt = 0; rt < 4; ++rt) {
                float vv[4];
#pragma unroll
                for (int rg = 0; rg < 4; ++rg) {
                    float v = acc[rt][ct][rg] + bias;
                    vv[rg] = (v >= 0.f) ? v : 0.2f * v;
                }
                if (n0 < 192) {
#pragma unroll
                    for (int rg = 0; rg < 4; ++rg)
                        q[(rt * 16 + gi * 4 + rg) * 200 + n0 + li] = (bf16)(vv[rg] * SCALE);
                } else if (n0 < 384) {
#pragma unroll
                    for (int rg = 0; rg < 4; ++rg)
                        kb[(rt * 16 + gi * 4 + rg) * 200 + (n0 - 192) + li] = (bf16)vv[rg];
                } else {
                    int cc = n0 - 384;
                    int hh = cc >> 5, d0 = cc & 31;
                    bf16x4 v4;
#pragma unroll
                    for (int rg = 0; rg < 4; ++rg) v4[rg] = (bf16)vv[rg];
                    *(bf16x4*)&vt[(hh * 32 + d0 + li) * 72 + rt * 16 + gi * 4] = v4;
                }
            }
        }
        __syncthreads();

        // prefetch next window's x (consumed after attention)
        bool pf = (it + 1 < nw);
        float4 px[12];
        if (pf) {
            const float4* xg = (const float4*)(x + (size_t)(win + 1) * 12288);
#pragma unroll
            for (int i = 0; i < 12; ++i) px[i] = xg[i * 256 + tid];
        }

        // ================= attention: 3 (head, n-half) jobs per wave =================
        bf16* ol = xb;  // out tile reuses the consumed x buffer
        for (int jj = 0; jj < 3; ++jj) {
            int job = w * 3 + jj;
            int h   = job >> 1;
            int ct0 = (job & 1) * 2;
            // attn^T = k @ q^T  (M=m keys, N=n queries, K=d=32 -> one MFMA per tile)
            bf16x8 ak[4], bqf[2];
#pragma unroll
            for (int rt = 0; rt < 4; ++rt)
                ak[rt] = *(const bf16x8*)&kb[(rt * 16 + li) * 200 + h * 32 + gi * 8];
#pragma unroll
            for (int c2 = 0; c2 < 2; ++c2)
                bqf[c2] = *(const bf16x8*)&q[((ct0 + c2) * 16 + li) * 200 + h * 32 + gi * 8];
            f32x4 s[4][2];
#pragma unroll
            for (int rt = 0; rt < 4; ++rt)
#pragma unroll
                for (int c2 = 0; c2 < 2; ++c2)
                    s[rt][c2] = __builtin_amdgcn_mfma_f32_16x16x32_bf16(ak[rt], bqf[c2], fzero, 0, 0, 0);
            // + relative position bias (one dwordx4 per tile)
#pragma unroll
            for (int rt = 0; rt < 4; ++rt)
#pragma unroll
                for (int c2 = 0; c2 < 2; ++c2) {
                    f32x4 bv = *(const f32x4*)&biasB[h * 4096 + (rt * 4 + gi) * 256 + ((ct0 + c2) * 16 + li) * 4];
                    s[rt][c2] += bv;
                }
            // softmax over m (16 in-lane vals + shfl over lane-groups)
            float rs[2];
#pragma unroll
            for (int c2 = 0; c2 < 2; ++c2) {
                float m_ = -1e30f;
#pragma unroll
                for (int rt = 0; rt < 4; ++rt)
#pragma unroll
                    for (int rg = 0; rg < 4; ++rg) m_ = fmaxf(m_, s[rt][c2][rg]);
                m_ = fmaxf(m_, __shfl_xor(m_, 16));
                m_ = fmaxf(m_, __shfl_xor(m_, 32));
                float ss = 0.f;
#pragma unroll
                for (int rt = 0; rt < 4; ++rt)
#pragma unroll
                    for (int rg = 0; rg < 4; ++rg) {
                        float p = __expf(s[rt][c2][rg] - m_);
                        s[rt][c2][rg] = p;
                        ss += p;
                    }
                ss += __shfl_xor(ss, 16);
                ss += __shfl_xor(ss, 32);
                rs[c2] = 1.f / ss;
            }
            // P (unnormalized) -> n-major LDS, D-layout writes are contiguous b64
#pragma unroll
            for (int c2 = 0; c2 < 2; ++c2)
#pragma unroll
                for (int rt = 0; rt < 4; ++rt) {
                    bf16x4 pv;
#pragma unroll
                    for (int rg = 0; rg < 4; ++rg) pv[rg] = (bf16)s[rt][c2][rg];
                    *(bf16x4*)&Pw[(c2 * 16 + li) * 72 + rt * 16 + gi * 4] = pv;
                }
            // out^T = vT @ P^T  (M=d=32, N=n, K=m=64)
            f32x4 o[2][2];
#pragma unroll
            for (int dt = 0; dt < 2; ++dt)
#pragma unroll
                for (int c2 = 0; c2 < 2; ++c2) o[dt][c2] = fzero;
#pragma unroll
            for (int ks = 0; ks < 2; ++ks) {
                bf16x8 va[2], pb[2];
#pragma unroll
                for (int dt = 0; dt < 2; ++dt)
                    va[dt] = *(const bf16x8*)&vt[(h * 32 + dt * 16 + li) * 72 + ks * 32 + gi * 8];
#pragma unroll
                for (int c2 = 0; c2 < 2; ++c2)
                    pb[c2] = *(const bf16x8*)&Pw[(c2 * 16 + li) * 72 + ks * 32 + gi * 8];
#pragma unroll
                for (int dt = 0; dt < 2; ++dt)
#pragma unroll
                    for (int c2 = 0; c2 < 2; ++c2)
                        o[dt][c2] = __builtin_amdgcn_mfma_f32_16x16x32_bf16(va[dt], pb[c2], o[dt][c2], 0, 0, 0);
            }
            // normalize by 1/sum and write out tile [n][h*32+d]
#pragma unroll
            for (int dt = 0; dt < 2; ++dt)
#pragma unroll
                for (int c2 = 0; c2 < 2; ++c2) {
                    bf16x4 v4;
#pragma unroll
                    for (int rg = 0; rg < 4; ++rg) v4[rg] = (bf16)(o[dt][c2][rg] * rs[c2]);
                    *(bf16x4*)&ol[((ct0 + c2) * 16 + li) * 200 + h * 32 + dt * 16 + gi * 4] = v4;
                }
        }

        // write prefetched x into the other buffer (loads issued ~1 phase ago)
        if (pf) {
            bf16* xn = smem + (cur ? OFF_XB0 : OFF_XB1);
#pragma unroll
            for (int i = 0; i < 12; ++i) {
                int f = (i * 256 + tid) * 4;
                int r = f / 192, c = f % 192;
                bf16x4 v; v[0]=(bf16)px[i].x; v[1]=(bf16)px[i].y; v[2]=(bf16)px[i].z; v[3]=(bf16)px[i].w;
                *(bf16x4*)&xn[r * 200 + c] = v;
            }
        }
        __syncthreads();

        // ================= proj GEMM: [64,192]x[192,192] + bias -> f32 out =================
        f32x4 pacc[4][3];
#pragma unroll
        for (int rt = 0; rt < 4; ++rt)
#pragma unroll
            for (int ct = 0; ct < 3; ++ct) pacc[rt][ct] = fzero;
#pragma unroll
        for (int kk = 0; kk < 6; ++kk) {
            bf16x8 a[4], bw[3];
#pragma unroll
            for (int rt = 0; rt < 4; ++rt)
                a[rt] = *(const bf16x8*)&ol[(rt * 16 + li) * 200 + kk * 32 + gi * 8];
#pragma unroll
            for (int ct = 0; ct < 3; ++ct)
                bw[ct] = *(const bf16x8*)&projT[(size_t)(w * 48 + ct * 16 + li) * 192 + kk * 32 + gi * 8];
#pragma unroll
            for (int ct = 0; ct < 3; ++ct)
#pragma unroll
                for (int rt = 0; rt < 4; ++rt)
                    pacc[rt][ct] = __builtin_amdgcn_mfma_f32_16x16x32_bf16(a[rt], bw[ct], pacc[rt][ct], 0, 0, 0);
        }
        float* og = outg + (size_t)win * 12288;
#pragma unroll
        for (int ct = 0; ct < 3; ++ct) {
            int n = w * 48 + ct * 16 + li;
            float pb_ = proj_b[n];
#pragma unroll
            for (int rt = 0; rt < 4; ++rt)
#pragma unroll
                for (int rg = 0; rg < 4; ++rg)
                    og[(rt * 16 + gi * 4 + rg) * 192 + n] = pacc[rt][ct][rg] + pb_;
        }

        cur ^= 1;
    }
}

extern "C" void kernel_launch(void* const* d_in, const int* in_sizes, int n_in,
                              void* d_out, int out_size, void* d_ws, size_t ws_size,
                              hipStream_t stream)
{
    const float* x          = (const float*)d_in[0];
    const float* wq         = (const float*)d_in[1];
    const float* bq         = (const float*)d_in[2];
    const float* wkv        = (const float*)d_in[3];
    const float* bkv        = (const float*)d_in[4];
    const float* bias_table = (const float*)d_in[5];
    const float* proj_w     = (const float*)d_in[6];
    const float* proj_b     = (const float*)d_in[7];
    float* out = (float*)d_out;

    int B = in_sizes[0] / (64 * 192);

    bf16*  wqkvT = (bf16*)d_ws;
    bf16*  projT = (bf16*)((char*)d_ws + 221184);
    float* biasB = (float*)((char*)d_ws + 294912);

    wattn_prep<<<672, 256, 0, stream>>>(wq, wkv, bias_table, proj_w, wqkvT, projT, biasB);

    int nIter = (B + 255) / 256;
    wattn_main<<<256, 256, 0, stream>>>(x, wqkvT, bq, bkv, projT, biasB, proj_b, out, B, nIter);
}

// Round 2
// 238.852 us; speedup vs baseline: 3.3838x; 3.3838x over previous
//
#include <hip/hip_runtime.h>
#include <hip/hip_bf16.h>

typedef __bf16 bf16;
typedef bf16 bf16x8 __attribute__((ext_vector_type(8)));
typedef bf16 bf16x4 __attribute__((ext_vector_type(4)));
typedef short s16x4 __attribute__((ext_vector_type(4)));
typedef float f32x4 __attribute__((ext_vector_type(4)));

#define SCALE 0.17677669529663687f  // 1/sqrt(32)

// LDS element offsets (bf16 units)
// R_b: x -> q -> attn-out   [64][200]
// R_k: k [64][200] ; after proj, f32 out overlays R_k..R_v (53248 B >= 49152 B)
// R_v: vT [6 heads][32 d][72]
#define OFF_B 0
#define OFF_K 12800
#define OFF_V 25600
#define SMEM_ELEMS 39424   // 78848 B -> 2 blocks/CU

#if defined(__has_builtin)
#if __has_builtin(__builtin_amdgcn_mfma_f32_16x16x16bf16_1k)
#define HAS_MFMA16 1
#endif
#endif

// ---------------- prep kernel: weight transpose->bf16, bias gather ----------------
// ws layout (bytes): wqkvT bf16 [576][192] @0 ; projT bf16 [192][192] @221184 ;
//                    biasB f32  [6][16][64][4] @294912
__global__ void wattn_prep(const float* __restrict__ wq, const float* __restrict__ wkv,
                           const float* __restrict__ bias_table, const float* __restrict__ proj_w,
                           bf16* __restrict__ wqkvT, bf16* __restrict__ projT,
                           float* __restrict__ biasB)
{
    int t = blockIdx.x * 256 + threadIdx.x;
    if (t < 110592) {                       // wqkvT[n][k] = W[k][n]
        int n = t / 192, k = t % 192;
        float v = (n < 192) ? wq[k * 192 + n] : wkv[k * 384 + (n - 192)];
        wqkvT[t] = (bf16)v;
    } else if (t < 147456) {                // projT[n][k] = proj_w[k][n]
        int e = t - 110592;
        int n = e / 192, k = e % 192;
        projT[e] = (bf16)proj_w[k * 192 + n];
    } else if (t < 172032) {                // biasB[h][m>>2][n][m&3] = bias[h][n][m]
        int e = t - 147456;
        int h  = e >> 12;
        int mb = (e >> 8) & 15;
        int n  = (e >> 2) & 63;
        int mr = e & 3;
        int m  = mb * 4 + mr;
        int idx = ((n & 7) - (m & 7) + 7) * 15 + ((n >> 3) - (m >> 3) + 7);
        biasB[e] = bias_table[idx * 6 + h];
    }
}

// ---------------- fused main kernel: one window per block ----------------
__global__ __launch_bounds__(256, 2)
void wattn_main(const float* __restrict__ x, const bf16* __restrict__ wqkvT,
                const float* __restrict__ bq, const float* __restrict__ bkv,
                const bf16* __restrict__ projT, const float* __restrict__ biasB,
                const float* __restrict__ proj_b, float* __restrict__ outg, int B)
{
    __shared__ __align__(16) bf16 smem[SMEM_ELEMS];
    const int tid = threadIdx.x;
    const int li  = tid & 15;
    const int gi  = (tid >> 4) & 3;
    const int w   = tid >> 6;
    const int win = blockIdx.x;
    if (win >= B) return;

    bf16* xq = smem + OFF_B;
    bf16* kb = smem + OFF_K;
    bf16* vt = smem + OFF_V;

    const f32x4 fzero = {0.f, 0.f, 0.f, 0.f};

    // ---- stage x (f32 global -> bf16 LDS [64][200]) ----
    {
        const float4* xg = (const float4*)(x + (size_t)win * 12288);
#pragma unroll
        for (int i = 0; i < 12; ++i) {
            float4 p = xg[i * 256 + tid];
            int f = (i * 256 + tid) * 4;
            int r = f / 192, c = f % 192;
            bf16x4 v; v[0]=(bf16)p.x; v[1]=(bf16)p.y; v[2]=(bf16)p.z; v[3]=(bf16)p.w;
            *(bf16x4*)&xq[r * 200 + c] = v;
        }
    }
    __syncthreads();                                     // B1

    // ---- QKV GEMM: [64,192]x[192,576], col tiles T = w + 4*c (balanced q/k/v) ----
    f32x4 acc[4][9];
#pragma unroll
    for (int rt = 0; rt < 4; ++rt)
#pragma unroll
        for (int c = 0; c < 9; ++c) acc[rt][c] = fzero;
#pragma unroll
    for (int kk = 0; kk < 6; ++kk) {
        bf16x8 a[4], bw[9];
#pragma unroll
        for (int rt = 0; rt < 4; ++rt)
            a[rt] = *(const bf16x8*)&xq[(rt * 16 + li) * 200 + kk * 32 + gi * 8];
#pragma unroll
        for (int c = 0; c < 9; ++c) {
            int T = w + 4 * c;
            bw[c] = *(const bf16x8*)&wqkvT[(size_t)(T * 16 + li) * 192 + kk * 32 + gi * 8];
        }
#pragma unroll
        for (int c = 0; c < 9; ++c)
#pragma unroll
            for (int rt = 0; rt < 4; ++rt)
                acc[rt][c] = __builtin_amdgcn_mfma_f32_16x16x32_bf16(a[rt], bw[c], acc[rt][c], 0, 0, 0);
    }
    __syncthreads();                                     // B2 (xq reads done; q may overwrite)

    // ---- epilogue: bias + leaky; q(*SCALE)->xq, k->kb, v->vT ----
#pragma unroll
    for (int c = 0; c < 9; ++c) {
        int T = w + 4 * c;
        int n0 = T * 16;
        float bias = (n0 < 192) ? bq[n0 + li] : bkv[n0 - 192 + li];
#pragma unroll
        for (int rt = 0; rt < 4; ++rt) {
            float vv[4];
#pragma unroll
            for (int rg = 0; rg < 4; ++rg) {
                float v = acc[rt][c][rg] + bias;
                vv[rg] = (v >= 0.f) ? v : 0.2f * v;
            }
            if (T < 12) {
#pragma unroll
                for (int rg = 0; rg < 4; ++rg)
                    xq[(rt * 16 + gi * 4 + rg) * 200 + n0 + li] = (bf16)(vv[rg] * SCALE);
            } else if (T < 24) {
#pragma unroll
                for (int rg = 0; rg < 4; ++rg)
                    kb[(rt * 16 + gi * 4 + rg) * 200 + (n0 - 192) + li] = (bf16)vv[rg];
            } else {
                int cc = n0 - 384;
                int hh = cc >> 5, d0 = cc & 31;
                bf16x4 v4;
#pragma unroll
                for (int rg = 0; rg < 4; ++rg) v4[rg] = (bf16)vv[rg];
                *(bf16x4*)&vt[(hh * 32 + d0 + li) * 72 + rt * 16 + gi * 4] = v4;
            }
        }
    }
    __syncthreads();                                     // B3

    // ---- attention: 3 (head, n-half) jobs per wave; P stays in registers ----
    bf16x4 obf[3][2][2];
    for (int jj = 0; jj < 3; ++jj) {
        int job = w * 3 + jj;
        int h   = job >> 1;
        int ct0 = (job & 1) * 2;

        // attn^T = k @ q^T  (M=keys, N=queries, K=d=32)
        bf16x8 ak[4], bqf[2];
#pragma unroll
        for (int rt = 0; rt < 4; ++rt)
            ak[rt] = *(const bf16x8*)&kb[(rt * 16 + li) * 200 + h * 32 + gi * 8];
#pragma unroll
        for (int c2 = 0; c2 < 2; ++c2)
            bqf[c2] = *(const bf16x8*)&xq[((ct0 + c2) * 16 + li) * 200 + h * 32 + gi * 8];
        f32x4 s[4][2];
#pragma unroll
        for (int rt = 0; rt < 4; ++rt)
#pragma unroll
            for (int c2 = 0; c2 < 2; ++c2)
                s[rt][c2] = __builtin_amdgcn_mfma_f32_16x16x32_bf16(ak[rt], bqf[c2], fzero, 0, 0, 0);
        // + relative position bias
#pragma unroll
        for (int rt = 0; rt < 4; ++rt)
#pragma unroll
            for (int c2 = 0; c2 < 2; ++c2) {
                f32x4 bv = *(const f32x4*)&biasB[h * 4096 + (rt * 4 + gi) * 256 + ((ct0 + c2) * 16 + li) * 4];
                s[rt][c2] += bv;
            }
        // softmax over keys (16 in-lane + 2 shfl)
        float rs[2];
#pragma unroll
        for (int c2 = 0; c2 < 2; ++c2) {
            float m_ = -1e30f;
#pragma unroll
            for (int rt = 0; rt < 4; ++rt)
#pragma unroll
                for (int rg = 0; rg < 4; ++rg) m_ = fmaxf(m_, s[rt][c2][rg]);
            m_ = fmaxf(m_, __shfl_xor(m_, 16));
            m_ = fmaxf(m_, __shfl_xor(m_, 32));
            float ss = 0.f;
#pragma unroll
            for (int rt = 0; rt < 4; ++rt)
#pragma unroll
                for (int rg = 0; rg < 4; ++rg) {
                    float p = __expf(s[rt][c2][rg] - m_);
                    s[rt][c2][rg] = p;
                    ss += p;
                }
            ss += __shfl_xor(ss, 16);
            ss += __shfl_xor(ss, 32);
            rs[c2] = 1.f / ss;
        }

        f32x4 o[2][2];
#pragma unroll
        for (int dt = 0; dt < 2; ++dt)
#pragma unroll
            for (int c2 = 0; c2 < 2; ++c2) o[dt][c2] = fzero;

#if defined(HAS_MFMA16)
        // out^T = vT @ P^T with K=16 MFMA: P B-fragment == QK^T D-layout, zero movement.
#pragma unroll
        for (int ks = 0; ks < 4; ++ks) {
            s16x4 va[2], pb[2];
#pragma unroll
            for (int dt = 0; dt < 2; ++dt)
                va[dt] = *(const s16x4*)&vt[(h * 32 + dt * 16 + li) * 72 + ks * 16 + gi * 4];
#pragma unroll
            for (int c2 = 0; c2 < 2; ++c2) {
                bf16x4 b4;
#pragma unroll
                for (int rg = 0; rg < 4; ++rg) b4[rg] = (bf16)s[ks][c2][rg];
                pb[c2] = __builtin_bit_cast(s16x4, b4);
            }
#pragma unroll
            for (int dt = 0; dt < 2; ++dt)
#pragma unroll
                for (int c2 = 0; c2 < 2; ++c2)
                    o[dt][c2] = __builtin_amdgcn_mfma_f32_16x16x16bf16_1k(va[dt], pb[c2], o[dt][c2], 0, 0, 0);
        }
#else
        // fallback: build K=32 B-frags via cross-lane shuffles
#pragma unroll
        for (int c2 = 0; c2 < 2; ++c2) {
            unsigned pk[4][2];
#pragma unroll
            for (int rt = 0; rt < 4; ++rt)
#pragma unroll
                for (int pr = 0; pr < 2; ++pr) {
                    bf16 b0 = (bf16)s[rt][c2][2 * pr];
                    bf16 b1 = (bf16)s[rt][c2][2 * pr + 1];
                    unsigned short u0, u1;
                    __builtin_memcpy(&u0, &b0, 2);
                    __builtin_memcpy(&u1, &b1, 2);
                    pk[rt][pr] = (unsigned)u0 | ((unsigned)u1 << 16);
                }
#pragma unroll
            for (int ks = 0; ks < 2; ++ks) {
                union { unsigned u[4]; bf16x8 v; } bu;
#pragma unroll
                for (int p = 0; p < 4; ++p) {
                    int srcLane = li + 16 * (2 * (gi & 1) + (p >> 1));
                    unsigned vA = __shfl(pk[2 * ks][p & 1], srcLane);
                    unsigned vB = __shfl(pk[2 * ks + 1][p & 1], srcLane);
                    bu.u[p] = (gi >> 1) ? vB : vA;
                }
#pragma unroll
                for (int dt = 0; dt < 2; ++dt) {
                    bf16x8 va = *(const bf16x8*)&vt[(h * 32 + dt * 16 + li) * 72 + ks * 32 + gi * 8];
                    o[dt][c2] = __builtin_amdgcn_mfma_f32_16x16x32_bf16(va, bu.v, o[dt][c2], 0, 0, 0);
                }
            }
        }
#endif
        // normalize, keep attn-out in registers (bf16)
#pragma unroll
        for (int dt = 0; dt < 2; ++dt)
#pragma unroll
            for (int c2 = 0; c2 < 2; ++c2) {
                bf16x4 v4;
#pragma unroll
                for (int rg = 0; rg < 4; ++rg) v4[rg] = (bf16)(o[dt][c2][rg] * rs[c2]);
                obf[jj][dt][c2] = v4;
            }
    }
    __syncthreads();                                     // B4 (all q/k/vT reads done)

    // ---- attn-out -> xq region (over q) ----
#pragma unroll
    for (int jj = 0; jj < 3; ++jj) {
        int job = w * 3 + jj;
        int h   = job >> 1;
        int ct0 = (job & 1) * 2;
#pragma unroll
        for (int dt = 0; dt < 2; ++dt)
#pragma unroll
            for (int c2 = 0; c2 < 2; ++c2)
                *(bf16x4*)&xq[((ct0 + c2) * 16 + li) * 200 + h * 32 + dt * 16 + gi * 4] = obf[jj][dt][c2];
    }
    __syncthreads();                                     // B5

    // ---- proj GEMM: [64,192]x[192,192]; f32 result -> LDS overlay (R_k..R_v) ----
    f32x4 pacc[4][3];
#pragma unroll
    for (int rt = 0; rt < 4; ++rt)
#pragma unroll
        for (int ct = 0; ct < 3; ++ct) pacc[rt][ct] = fzero;
#pragma unroll
    for (int kk = 0; kk < 6; ++kk) {
        bf16x8 a[4], bw[3];
#pragma unroll
        for (int rt = 0; rt < 4; ++rt)
            a[rt] = *(const bf16x8*)&xq[(rt * 16 + li) * 200 + kk * 32 + gi * 8];
#pragma unroll
        for (int ct = 0; ct < 3; ++ct)
            bw[ct] = *(const bf16x8*)&projT[(size_t)(w * 48 + ct * 16 + li) * 192 + kk * 32 + gi * 8];
#pragma unroll
        for (int ct = 0; ct < 3; ++ct)
#pragma unroll
            for (int rt = 0; rt < 4; ++rt)
                pacc[rt][ct] = __builtin_amdgcn_mfma_f32_16x16x32_bf16(a[rt], bw[ct], pacc[rt][ct], 0, 0, 0);
    }
    // f32 stage into R_k..R_v overlay — different region from xq, no barrier needed
    {
        float* of = (float*)(smem + OFF_K);
#pragma unroll
        for (int ct = 0; ct < 3; ++ct) {
            int n = w * 48 + ct * 16 + li;
            float pb_ = proj_b[n];
#pragma unroll
            for (int rt = 0; rt < 4; ++rt)
#pragma unroll
                for (int rg = 0; rg < 4; ++rg)
                    of[(rt * 16 + gi * 4 + rg) * 192 + n] = pacc[rt][ct][rg] + pb_;
        }
    }
    __syncthreads();                                     // B6

    // ---- coalesced copy-out: full float4 lines ----
    {
        const float4* os = (const float4*)(smem + OFF_K);
        float4* og = (float4*)(outg + (size_t)win * 12288);
#pragma unroll
        for (int i = 0; i < 12; ++i)
            og[i * 256 + tid] = os[i * 256 + tid];
    }
}

extern "C" void kernel_launch(void* const* d_in, const int* in_sizes, int n_in,
                              void* d_out, int out_size, void* d_ws, size_t ws_size,
                              hipStream_t stream)
{
    const float* x          = (const float*)d_in[0];
    const float* wq         = (const float*)d_in[1];
    const float* bq         = (const float*)d_in[2];
    const float* wkv        = (const float*)d_in[3];
    const float* bkv        = (const float*)d_in[4];
    const float* bias_table = (const float*)d_in[5];
    const float* proj_w     = (const float*)d_in[6];
    const float* proj_b     = (const float*)d_in[7];
    float* out = (float*)d_out;

    int B = in_sizes[0] / (64 * 192);

    bf16*  wqkvT = (bf16*)d_ws;
    bf16*  projT = (bf16*)((char*)d_ws + 221184);
    float* biasB = (float*)((char*)d_ws + 294912);

    wattn_prep<<<672, 256, 0, stream>>>(wq, wkv, bias_table, proj_w, wqkvT, projT, biasB);

    wattn_main<<<B, 256, 0, stream>>>(x, wqkvT, bq, bkv, projT, biasB, proj_b, out, B);
}